// Round 10
// baseline (340.745 us; speedup 1.0000x reference)
//
#include <hip/hip_runtime.h>

#define BATCH 4096
#define DM 768
#define LTOT 10240
#define NG 124

typedef __bf16 bf16x8 __attribute__((ext_vector_type(8)));
typedef short short8 __attribute__((ext_vector_type(8)));
typedef float f32x4 __attribute__((ext_vector_type(4)));

struct Ptr5 { const float* p[5]; };

__device__ __forceinline__ unsigned short f2bf(float f) {
    unsigned u = __builtin_bit_cast(unsigned, f);
    unsigned r = (u + 0x7FFFu + ((u >> 16) & 1u)) >> 16;   // RNE
    return (unsigned short)r;
}

__device__ __forceinline__ short8 pack8(float4 a, float4 b) {
    union { unsigned short u[8]; short8 s; } o;
    o.u[0] = f2bf(a.x); o.u[1] = f2bf(a.y); o.u[2] = f2bf(a.z); o.u[3] = f2bf(a.w);
    o.u[4] = f2bf(b.x); o.u[5] = f2bf(b.y); o.u[6] = f2bf(b.z); o.u[7] = f2bf(b.w);
    return o.s;
}

// ---------------- fat prep kernel (single dispatch, no atomics-needing-init) ----
// bx [0,32):       gate GEMM: relu(x@enc^T - b) -> gate_ws + d_out gates + slot stats
// bx [32,1952):    V{g}/U{g} conv (2048 float4/block), norm partial -> vslot/uslot
// bx [1952,2336):  x -> xb bf16 cast

__global__ __launch_bounds__(256) void prep_k(const float* __restrict__ x,
                                              Ptr5 vp, Ptr5 up, Ptr5 ep, Ptr5 bp,
                                              unsigned short* __restrict__ vb,
                                              unsigned short* __restrict__ w2t,
                                              unsigned short* __restrict__ xb,
                                              float* __restrict__ gate_ws,
                                              float* __restrict__ outg,
                                              float* __restrict__ vslot,
                                              float* __restrict__ uslot,
                                              float* __restrict__ gslot,
                                              float* __restrict__ aslot) {
    const int basen[5] = {0, 4, 12, 28, 60};
    int bx = blockIdx.x;
    int tid = threadIdx.x;
    if (bx < 32) {
        // ---- gate GEMM (M=128 rows per block, N=128 cols (124 valid), K=768) ----
        __shared__ unsigned short lA[128 * 64];
        __shared__ unsigned short lB[128 * 64];
        __shared__ float sgs[128];
        __shared__ float sac;
        int wave = tid >> 6, lane = tid & 63;
        int wm = wave >> 1, wn = wave & 1;
        int lan15 = lane & 15, quad = lane >> 4;
        int sw = lan15 & 7;
        int m0 = bx * 128;
        f32x4 acc[4][4] = {};
        for (int k0 = 0; k0 < DM; k0 += 64) {
            __syncthreads();
            #pragma unroll
            for (int i = 0; i < 4; i++) {
                int gidx = i * 256 + tid;           // granule index 0..1023
                int row = gidx >> 3, kb = gidx & 7;
                int r7 = row & 7;
                int la = (row >> 3) * 512 + r7 * 64 + (kb ^ r7) * 8;
                // A: x rows
                int sidx = (m0 + row) * 192 + (k0 >> 2) + kb * 2;
                float4 a0 = ((const float4*)x)[sidx];
                float4 a1 = ((const float4*)x)[sidx + 1];
                *(short8*)(lA + la) = pack8(a0, a1);
                // B: enc rows (zero-pad n>=124)
                float4 b0 = {0.f, 0.f, 0.f, 0.f}, b1 = {0.f, 0.f, 0.f, 0.f};
                if (row < NG) {
                    int g = (row < 4) ? 0 : (row < 12) ? 1 : (row < 28) ? 2 :
                            (row < 60) ? 3 : 4;
                    int ni = row - basen[g];
                    int eidx = ni * 192 + (k0 >> 2) + kb * 2;
                    b0 = ((const float4*)ep.p[g])[eidx];
                    b1 = ((const float4*)ep.p[g])[eidx + 1];
                }
                *(short8*)(lB + la) = pack8(b0, b1);
            }
            __syncthreads();
            #pragma unroll
            for (int kk = 0; kk < 2; kk++) {
                int kb = kk * 4 + quad;
                int kel = (kb ^ sw) * 8;
                bf16x8 af[4], bfr[4];
                #pragma unroll
                for (int t = 0; t < 4; t++) {
                    short8 ra = *(const short8*)(lA + (wm * 64 + t * 16 + lan15) * 64 + kel);
                    short8 rb = *(const short8*)(lB + (wn * 64 + t * 16 + lan15) * 64 + kel);
                    af[t]  = __builtin_bit_cast(bf16x8, ra);
                    bfr[t] = __builtin_bit_cast(bf16x8, rb);
                }
                #pragma unroll
                for (int mt = 0; mt < 4; mt++)
                    #pragma unroll
                    for (int nt = 0; nt < 4; nt++)
                        acc[mt][nt] = __builtin_amdgcn_mfma_f32_16x16x32_bf16(
                            af[mt], bfr[nt], acc[mt][nt], 0, 0, 0);
            }
        }
        // epilogue: relu(acc - bias), write gate_ws + out gates, slot stats
        if (tid < 128) sgs[tid] = 0.f;
        if (tid == 0) sac = 0.f;
        __syncthreads();
        const size_t baseg[5] = {3145730ull, 3145730ull + 16384, 3145730ull + 49152,
                                 3145730ull + 114688, 3145730ull + 245760};
        float cnt = 0.f;
        #pragma unroll
        for (int nt = 0; nt < 4; nt++) {
            int col = wn * 64 + nt * 16 + lan15;
            float cs = 0.f;
            if (col < NG) {
                int g = (col < 4) ? 0 : (col < 12) ? 1 : (col < 28) ? 2 :
                        (col < 60) ? 3 : 4;
                int ni = col - basen[g];
                int w = 4 << g;
                float bv = bp.p[g][ni];
                #pragma unroll
                for (int mt = 0; mt < 4; mt++) {
                    int r0 = m0 + wm * 64 + mt * 16 + quad * 4;
                    #pragma unroll
                    for (int rg = 0; rg < 4; rg++) {
                        float pre = acc[mt][nt][rg] - bv;
                        float gt = pre > 0.f ? pre : 0.f;
                        gate_ws[(size_t)(r0 + rg) * NG + col] = gt;
                        outg[baseg[g] + (size_t)(r0 + rg) * w + ni] = gt;
                        cs += gt;
                        if (pre > 0.f) cnt += 1.f;
                    }
                }
                cs += __shfl_xor(cs, 16);
                cs += __shfl_xor(cs, 32);
                if (quad == 0) atomicAdd(&sgs[col], cs);
            }
        }
        #pragma unroll
        for (int off = 32; off > 0; off >>= 1) cnt += __shfl_xor(cnt, off);
        if (lane == 0) atomicAdd(&sac, cnt);
        __syncthreads();
        if (tid < NG) gslot[bx * NG + tid] = sgs[tid];
        if (tid == 0) aslot[bx] = sac;
    } else if (bx < 1952) {
        // ---- streaming V/U conversion + norm slots ----
        __shared__ float swave[4];
        int cb = bx - 32;
        int isV = cb < 960;
        int wb = isV ? cb : cb - 960;       // 0..959
        int g = wb / 192;
        int within = wb - g * 192;
        const float* src = isV ? vp.p[g] : up.p[g];
        int r = 512 >> g, lr = 9 - g;
        float ss = 0.f;
        #pragma unroll
        for (int i = 0; i < 8; i++) {
            int j = within * 2048 + i * 256 + tid;
            float4 v = ((const float4*)src)[j];
            ss += v.x*v.x + v.y*v.y + v.z*v.z + v.w*v.w;
            ushort4 o;
            o.x = f2bf(v.x); o.y = f2bf(v.y); o.z = f2bf(v.z); o.w = f2bf(v.w);
            if (isV) {
                ((ushort4*)vb)[(size_t)(g * 192 + within) * 2048 + i * 256 + tid] = o;
            } else {
                int idx = j * 4;
                int rr = idx & (r - 1);
                int t2 = idx >> lr;
                int d  = t2 % DM;
                int n  = t2 / DM;
                size_t dst = (size_t)d * LTOT + (size_t)(g << 11) + (size_t)n * r + rr;
                *(ushort4*)(w2t + dst) = o;
            }
        }
        #pragma unroll
        for (int off = 32; off > 0; off >>= 1) ss += __shfl_down(ss, off);
        if ((tid & 63) == 0) swave[tid >> 6] = ss;
        __syncthreads();
        if (tid == 0) {
            float t = (swave[0] + swave[1]) + (swave[2] + swave[3]);
            (isV ? vslot : uslot)[wb] = t;
        }
    } else {
        // ---- x -> xb ----
        int base = (bx - 1952) * 2048;
        #pragma unroll
        for (int i = 0; i < 8; i++) {
            int j = base + i * 256 + tid;
            float4 v = ((const float4*)x)[j];
            ushort4 o;
            o.x = f2bf(v.x); o.y = f2bf(v.y); o.z = f2bf(v.z); o.w = f2bf(v.w);
            ((ushort4*)xb)[j] = o;
        }
    }
}

// ---------------- MFMA GEMM (NT: C = A @ B^T) ----------------
// ROWSx64 bf16 tile staged via async global->LDS, 16B/lane.
// XOR swizzle: physical granule (row, kb^(row&7)) holds logical (row, kb).
template <int ROWS, int NT>
__device__ __forceinline__ void stage(const unsigned short* __restrict__ src, int ld,
                                      unsigned short* lds, int wv, int lane) {
    int rsub = lane >> 3;
    int colb = ((lane ^ rsub) & 7) * 8;
    #pragma unroll
    for (int i = 0; i < ROWS * 8 / NT; i++) {
        int c = i * (NT / 64) + wv;
        const unsigned short* gp = src + (size_t)(c * 8 + rsub) * ld + colb;
        __builtin_amdgcn_global_load_lds((const __attribute__((address_space(1))) void*)gp,
                                         (__attribute__((address_space(3))) void*)(lds + c * 512),
                                         16, 0, 0);
    }
}

// EPI=0: gate + bf16 Hg via LDS-transposed wide-store epilogue.
// EPI=1: plain fp32 split-K partial stores (separate reduce kernel — fused
//        last-block reduce regressed 3x: device __threadfence drains the
//        non-coherent per-XCD L2s to HBM).
template <int BM, int BN, int EPI, int NT>
__global__ __launch_bounds__(NT) void gemm_nt(const unsigned short* __restrict__ A,
                                              const unsigned short* __restrict__ Bm,
                                              int Kblk, int lda, int ldb,
                                              void* __restrict__ Cout,
                                              const float* __restrict__ gate, int ldc) {
    __shared__ unsigned short lA[BM * 64];
    __shared__ unsigned short lB[BN * 64];
    int tid = threadIdx.x, wave = tid >> 6, lane = tid & 63;
    constexpr int WN = BN / 64;
    int wm = wave / WN, wn = wave % WN;
    int m0 = blockIdx.x * BM, n0 = blockIdx.y * BN;    // m is the FAST grid dim
    A  += (size_t)m0 * lda + (size_t)blockIdx.z * Kblk;
    Bm += (size_t)n0 * ldb + (size_t)blockIdx.z * Kblk;
    f32x4 acc[4][4] = {};
    int lan15 = lane & 15, quad = lane >> 4;
    int sw = lan15 & 7;

    for (int k0 = 0; k0 < Kblk; k0 += 64) {
        stage<BM, NT>(A + k0, lda, lA, wave, lane);
        stage<BN, NT>(Bm + k0, ldb, lB, wave, lane);
        __syncthreads();
        #pragma unroll
        for (int kk = 0; kk < 2; kk++) {
            int kb = kk * 4 + quad;
            int kel = (kb ^ sw) * 8;
            bf16x8 af[4], bfr[4];
            #pragma unroll
            for (int t = 0; t < 4; t++) {
                short8 ra = *(const short8*)(lA + (size_t)(wm * 64 + t * 16 + lan15) * 64 + kel);
                short8 rb = *(const short8*)(lB + (size_t)(wn * 64 + t * 16 + lan15) * 64 + kel);
                af[t]  = __builtin_bit_cast(bf16x8, ra);
                bfr[t] = __builtin_bit_cast(bf16x8, rb);
            }
            #pragma unroll
            for (int mt = 0; mt < 4; mt++)
                #pragma unroll
                for (int nt = 0; nt < 4; nt++)
                    acc[mt][nt] = __builtin_amdgcn_mfma_f32_16x16x32_bf16(af[mt], bfr[nt],
                                                                          acc[mt][nt], 0, 0, 0);
        }
        __syncthreads();
    }

    const int basen[5] = {0, 4, 12, 28, 60};
    if (EPI == 0) {
        unsigned short* H = (unsigned short*)Cout;
        #pragma unroll
        for (int mt = 0; mt < 4; mt++) {
            __syncthreads();
            #pragma unroll
            for (int nt = 0; nt < 4; nt++) {
                int col = n0 + wn * 64 + nt * 16 + lan15;
                int g = col >> 11;
                int ngl = basen[g] + ((col & 2047) >> (9 - g));
                #pragma unroll
                for (int rg = 0; rg < 4; rg++) {
                    int grow = m0 + wm * 64 + mt * 16 + quad * 4 + rg;
                    float gv = gate[(size_t)grow * NG + ngl];
                    lA[wave * 1024 + (quad * 4 + rg) * 64 + nt * 16 + lan15] =
                        f2bf(acc[mt][nt][rg] * gv);
                }
            }
            __syncthreads();
            #pragma unroll
            for (int i = 0; i < 2; i++) {
                int f = i * NT + tid;
                int R = f >> 5;
                int u = f & 31;
                int wv2 = ((R >> 4) << 2) + (u >> 3);
                short8 vread = *(const short8*)(lA + wv2 * 1024 + (R & 15) * 64 + (u & 7) * 8);
                int grow = m0 + (R >> 4) * 64 + mt * 16 + (R & 15);
                *(short8*)(H + (size_t)grow * ldc + n0 + u * 8) = vread;
            }
        }
    } else {
        float* P = (float*)Cout;
        P += (size_t)blockIdx.z * gridDim.x * BM * ldc;
        #pragma unroll
        for (int nt = 0; nt < 4; nt++) {
            int col = n0 + wn * 64 + nt * 16 + lan15;
            #pragma unroll
            for (int mt = 0; mt < 4; mt++) {
                int r0 = m0 + wm * 64 + mt * 16 + quad * 4;
                #pragma unroll
                for (int rg = 0; rg < 4; rg++)
                    P[(size_t)(r0 + rg) * ldc + col] = acc[mt][nt][rg];
            }
        }
    }
}

// ---------------- split-K reduce + fused final stats (block 0) ----------------

__global__ __launch_bounds__(256) void reduce_k(const float4* __restrict__ P,
                                                float4* __restrict__ out, int quarter,
                                                const float* __restrict__ vslot,
                                                const float* __restrict__ uslot,
                                                const float* __restrict__ gslot,
                                                const float* __restrict__ aslot,
                                                float* __restrict__ o2) {
    int i = blockIdx.x * 256 + threadIdx.x;
    float4 a = P[i], b = P[i + quarter], c = P[i + 2 * quarter], d = P[i + 3 * quarter];
    float4 o;
    o.x = (a.x + b.x) + (c.x + d.x);
    o.y = (a.y + b.y) + (c.y + d.y);
    o.z = (a.z + b.z) + (c.z + d.z);
    o.w = (a.w + b.w) + (c.w + d.w);
    out[i] = o;
    if (blockIdx.x == 0) {
        __shared__ float sh[128];
        const int basen[5] = {0, 4, 12, 28, 60};
        int t = threadIdx.x;
        if (t < 128) {
            float v = 0.f;
            if (t < NG) {
                int g = (t < 4) ? 0 : (t < 12) ? 1 : (t < 28) ? 2 : (t < 60) ? 3 : 4;
                int nloc = t - basen[g];
                int bpseg = 48 >> g;
                float vs = 0.f, us = 0.f;
                int base = g * 192 + nloc * bpseg;
                for (int j = 0; j < bpseg; j++) { vs += vslot[base + j]; us += uslot[base + j]; }
                float gs = 0.f;
                for (int bb = 0; bb < 32; bb++) gs += gslot[bb * NG + t];
                float rr = (float)(512 >> g);
                float mean = gs * (1.0f / BATCH);
                float frob = sqrtf(us * vs) / sqrtf(768.0f * rr);
                v = tanhf(mean) * frob;
            }
            sh[t] = v;
        }
        if (t == 128) {
            float asum = 0.f;
            for (int bb = 0; bb < 32; bb++) asum += aslot[bb];
            o2[1] = asum * (1.0f / BATCH);
        }
        __syncthreads();
        for (int s = 64; s > 0; s >>= 1) {
            if (threadIdx.x < s) sh[threadIdx.x] += sh[threadIdx.x + s];
            __syncthreads();
        }
        if (threadIdx.x == 0) o2[0] = sh[0];
    }
}

// ---------------- launcher ----------------

extern "C" void kernel_launch(void* const* d_in, const int* in_sizes, int n_in,
                              void* d_out, int out_size, void* d_ws, size_t ws_size,
                              hipStream_t stream) {
    const float* x = (const float*)d_in[0];
    Ptr5 vp, up, ep, bp;
    for (int g = 0; g < 5; g++) {
        vp.p[g] = (const float*)d_in[1 + 4 * g];
        up.p[g] = (const float*)d_in[2 + 4 * g];
        ep.p[g] = (const float*)d_in[3 + 4 * g];
        bp.p[g] = (const float*)d_in[4 + 4 * g];
    }
    float* out = (float*)d_out;
    char* ws = (char*)d_ws;
    size_t off = 0;
    unsigned short* xb   = (unsigned short*)(ws + off); off += (size_t)BATCH * DM * 2;
    unsigned short* vb   = (unsigned short*)(ws + off); off += (size_t)LTOT * DM * 2;
    unsigned short* w2t  = (unsigned short*)(ws + off); off += (size_t)LTOT * DM * 2;
    float* gate_ws       = (float*)(ws + off);          off += (size_t)BATCH * NG * 4;
    float* vslot         = (float*)(ws + off);          off += 960 * 4;
    float* uslot         = (float*)(ws + off);          off += 960 * 4;
    float* gslot         = (float*)(ws + off);          off += 32 * NG * 4;
    float* aslot         = (float*)(ws + off);          off += 32 * 4 + 256;
    size_t fixed = off;
    int CB = BATCH;
    while (CB > 128 && fixed + (size_t)CB * LTOT * 2 + 4ull * CB * DM * 4 > ws_size) CB >>= 1;
    unsigned short* Hg  = (unsigned short*)(ws + fixed);
    float* partial      = (float*)(ws + fixed + (size_t)CB * LTOT * 2);

    prep_k<<<dim3(2336), 256, 0, stream>>>(
        x, vp, up, ep, bp, vb, w2t, xb, gate_ws, out,
        vslot, uslot, gslot, aslot);

    int nch = BATCH / CB;
    for (int c = 0; c < nch; c++) {
        // GEMM1: Hg = gate .* (x @ V^T)   (M=CB, N=10240, K=768), m-fast grid
        gemm_nt<128, 256, 0, 512><<<dim3(CB / 128, LTOT / 256, 1), 512, 0, stream>>>(
            xb + (size_t)c * CB * DM, vb, DM, DM, DM,
            (void*)Hg, gate_ws + (size_t)c * CB * NG, LTOT);
        // GEMM2: out = Hg @ W2   (M=CB, N=768, K=10240), split-K=4 partials
        gemm_nt<128, 128, 1, 256><<<dim3(CB / 128, DM / 128, 4), 256, 0, stream>>>(
            Hg, w2t, LTOT / 4, LTOT, LTOT,
            (void*)partial, nullptr, DM);
        // reduce + fused final stats (block 0)
        reduce_k<<<dim3(CB * 192 / 256), 256, 0, stream>>>(
            (const float4*)partial, (float4*)(out + (size_t)c * CB * DM), CB * DM / 4,
            vslot, uslot, gslot, aslot, out + (size_t)BATCH * DM);
    }
}

// Round 11
// 335.582 us; speedup vs baseline: 1.0154x; 1.0154x over previous
//
#include <hip/hip_runtime.h>

#define BATCH 4096
#define DM 768
#define LTOT 10240
#define NG 124

typedef __bf16 bf16x8 __attribute__((ext_vector_type(8)));
typedef short short8 __attribute__((ext_vector_type(8)));
typedef float f32x4 __attribute__((ext_vector_type(4)));
typedef float f32x16 __attribute__((ext_vector_type(16)));

struct Ptr5 { const float* p[5]; };

__device__ __forceinline__ unsigned short f2bf(float f) {
    unsigned u = __builtin_bit_cast(unsigned, f);
    unsigned r = (u + 0x7FFFu + ((u >> 16) & 1u)) >> 16;   // RNE
    return (unsigned short)r;
}

__device__ __forceinline__ short8 pack8(float4 a, float4 b) {
    union { unsigned short u[8]; short8 s; } o;
    o.u[0] = f2bf(a.x); o.u[1] = f2bf(a.y); o.u[2] = f2bf(a.z); o.u[3] = f2bf(a.w);
    o.u[4] = f2bf(b.x); o.u[5] = f2bf(b.y); o.u[6] = f2bf(b.z); o.u[7] = f2bf(b.w);
    return o.s;
}

// ---------------- fat prep kernel (single dispatch, no atomics-needing-init) ----
// bx [0,32):       gate GEMM: relu(x@enc^T - b) -> gate_ws + d_out gates + slot stats
// bx [32,1952):    V{g}/U{g} conv (2048 float4/block), norm partial -> vslot/uslot
// bx [1952,2336):  x -> xb bf16 cast

__global__ __launch_bounds__(256) void prep_k(const float* __restrict__ x,
                                              Ptr5 vp, Ptr5 up, Ptr5 ep, Ptr5 bp,
                                              unsigned short* __restrict__ vb,
                                              unsigned short* __restrict__ w2t,
                                              unsigned short* __restrict__ xb,
                                              float* __restrict__ gate_ws,
                                              float* __restrict__ outg,
                                              float* __restrict__ vslot,
                                              float* __restrict__ uslot,
                                              float* __restrict__ gslot,
                                              float* __restrict__ aslot) {
    const int basen[5] = {0, 4, 12, 28, 60};
    int bx = blockIdx.x;
    int tid = threadIdx.x;
    if (bx < 32) {
        // ---- gate GEMM (M=128 rows per block, N=128 cols (124 valid), K=768) ----
        __shared__ unsigned short lA[128 * 64];
        __shared__ unsigned short lB[128 * 64];
        __shared__ float sgs[128];
        __shared__ float sac;
        int wave = tid >> 6, lane = tid & 63;
        int wm = wave >> 1, wn = wave & 1;
        int lan15 = lane & 15, quad = lane >> 4;
        int sw = lan15 & 7;
        int m0 = bx * 128;
        f32x4 acc[4][4] = {};
        for (int k0 = 0; k0 < DM; k0 += 64) {
            __syncthreads();
            #pragma unroll
            for (int i = 0; i < 4; i++) {
                int gidx = i * 256 + tid;           // granule index 0..1023
                int row = gidx >> 3, kb = gidx & 7;
                int r7 = row & 7;
                int la = (row >> 3) * 512 + r7 * 64 + (kb ^ r7) * 8;
                int sidx = (m0 + row) * 192 + (k0 >> 2) + kb * 2;
                float4 a0 = ((const float4*)x)[sidx];
                float4 a1 = ((const float4*)x)[sidx + 1];
                *(short8*)(lA + la) = pack8(a0, a1);
                float4 b0 = {0.f, 0.f, 0.f, 0.f}, b1 = {0.f, 0.f, 0.f, 0.f};
                if (row < NG) {
                    int g = (row < 4) ? 0 : (row < 12) ? 1 : (row < 28) ? 2 :
                            (row < 60) ? 3 : 4;
                    int ni = row - basen[g];
                    int eidx = ni * 192 + (k0 >> 2) + kb * 2;
                    b0 = ((const float4*)ep.p[g])[eidx];
                    b1 = ((const float4*)ep.p[g])[eidx + 1];
                }
                *(short8*)(lB + la) = pack8(b0, b1);
            }
            __syncthreads();
            #pragma unroll
            for (int kk = 0; kk < 2; kk++) {
                int kb = kk * 4 + quad;
                int kel = (kb ^ sw) * 8;
                bf16x8 af[4], bfr[4];
                #pragma unroll
                for (int t = 0; t < 4; t++) {
                    short8 ra = *(const short8*)(lA + (wm * 64 + t * 16 + lan15) * 64 + kel);
                    short8 rb = *(const short8*)(lB + (wn * 64 + t * 16 + lan15) * 64 + kel);
                    af[t]  = __builtin_bit_cast(bf16x8, ra);
                    bfr[t] = __builtin_bit_cast(bf16x8, rb);
                }
                #pragma unroll
                for (int mt = 0; mt < 4; mt++)
                    #pragma unroll
                    for (int nt = 0; nt < 4; nt++)
                        acc[mt][nt] = __builtin_amdgcn_mfma_f32_16x16x32_bf16(
                            af[mt], bfr[nt], acc[mt][nt], 0, 0, 0);
            }
        }
        if (tid < 128) sgs[tid] = 0.f;
        if (tid == 0) sac = 0.f;
        __syncthreads();
        const size_t baseg[5] = {3145730ull, 3145730ull + 16384, 3145730ull + 49152,
                                 3145730ull + 114688, 3145730ull + 245760};
        float cnt = 0.f;
        #pragma unroll
        for (int nt = 0; nt < 4; nt++) {
            int col = wn * 64 + nt * 16 + lan15;
            float cs = 0.f;
            if (col < NG) {
                int g = (col < 4) ? 0 : (col < 12) ? 1 : (col < 28) ? 2 :
                        (col < 60) ? 3 : 4;
                int ni = col - basen[g];
                int w = 4 << g;
                float bv = bp.p[g][ni];
                #pragma unroll
                for (int mt = 0; mt < 4; mt++) {
                    int r0 = m0 + wm * 64 + mt * 16 + quad * 4;
                    #pragma unroll
                    for (int rg = 0; rg < 4; rg++) {
                        float pre = acc[mt][nt][rg] - bv;
                        float gt = pre > 0.f ? pre : 0.f;
                        gate_ws[(size_t)(r0 + rg) * NG + col] = gt;
                        outg[baseg[g] + (size_t)(r0 + rg) * w + ni] = gt;
                        cs += gt;
                        if (pre > 0.f) cnt += 1.f;
                    }
                }
                cs += __shfl_xor(cs, 16);
                cs += __shfl_xor(cs, 32);
                if (quad == 0) atomicAdd(&sgs[col], cs);
            }
        }
        #pragma unroll
        for (int off = 32; off > 0; off >>= 1) cnt += __shfl_xor(cnt, off);
        if (lane == 0) atomicAdd(&sac, cnt);
        __syncthreads();
        if (tid < NG) gslot[bx * NG + tid] = sgs[tid];
        if (tid == 0) aslot[bx] = sac;
    } else if (bx < 1952) {
        // ---- streaming V/U conversion + norm slots ----
        __shared__ float swave[4];
        int cb = bx - 32;
        int isV = cb < 960;
        int wb = isV ? cb : cb - 960;       // 0..959
        int g = wb / 192;
        int within = wb - g * 192;
        const float* src = isV ? vp.p[g] : up.p[g];
        int r = 512 >> g, lr = 9 - g;
        float ss = 0.f;
        #pragma unroll
        for (int i = 0; i < 8; i++) {
            int j = within * 2048 + i * 256 + tid;
            float4 v = ((const float4*)src)[j];
            ss += v.x*v.x + v.y*v.y + v.z*v.z + v.w*v.w;
            ushort4 o;
            o.x = f2bf(v.x); o.y = f2bf(v.y); o.z = f2bf(v.z); o.w = f2bf(v.w);
            if (isV) {
                ((ushort4*)vb)[(size_t)(g * 192 + within) * 2048 + i * 256 + tid] = o;
            } else {
                int idx = j * 4;
                int rr = idx & (r - 1);
                int t2 = idx >> lr;
                int d  = t2 % DM;
                int n  = t2 / DM;
                size_t dst = (size_t)d * LTOT + (size_t)(g << 11) + (size_t)n * r + rr;
                *(ushort4*)(w2t + dst) = o;
            }
        }
        #pragma unroll
        for (int off = 32; off > 0; off >>= 1) ss += __shfl_down(ss, off);
        if ((tid & 63) == 0) swave[tid >> 6] = ss;
        __syncthreads();
        if (tid == 0) {
            float t = (swave[0] + swave[1]) + (swave[2] + swave[3]);
            (isV ? vslot : uslot)[wb] = t;
        }
    } else {
        // ---- x -> xb ----
        int base = (bx - 1952) * 2048;
        #pragma unroll
        for (int i = 0; i < 8; i++) {
            int j = base + i * 256 + tid;
            float4 v = ((const float4*)x)[j];
            ushort4 o;
            o.x = f2bf(v.x); o.y = f2bf(v.y); o.z = f2bf(v.z); o.w = f2bf(v.w);
            ((ushort4*)xb)[j] = o;
        }
    }
}

// ---------------- shared staging helper (XOR-swizzled async global->LDS) -------
template <int ROWS, int NT>
__device__ __forceinline__ void stage(const unsigned short* __restrict__ src, int ld,
                                      unsigned short* lds, int wv, int lane) {
    int rsub = lane >> 3;
    int colb = ((lane ^ rsub) & 7) * 8;
    #pragma unroll
    for (int i = 0; i < ROWS * 8 / NT; i++) {
        int c = i * (NT / 64) + wv;
        const unsigned short* gp = src + (size_t)(c * 8 + rsub) * ld + colb;
        __builtin_amdgcn_global_load_lds((const __attribute__((address_space(1))) void*)gp,
                                         (__attribute__((address_space(3))) void*)(lds + c * 512),
                                         16, 0, 0);
    }
}

// ---------------- GEMM1: 16x16x32 MFMA, gate + bf16 Hg LDS-transposed epilogue --
template <int BM, int BN, int NT>
__global__ __launch_bounds__(NT) void gemm_nt(const unsigned short* __restrict__ A,
                                              const unsigned short* __restrict__ Bm,
                                              int Kblk, int lda, int ldb,
                                              void* __restrict__ Cout,
                                              const float* __restrict__ gate, int ldc) {
    __shared__ unsigned short lA[BM * 64];
    __shared__ unsigned short lB[BN * 64];
    int tid = threadIdx.x, wave = tid >> 6, lane = tid & 63;
    constexpr int WN = BN / 64;
    int wm = wave / WN, wn = wave % WN;
    int m0 = blockIdx.x * BM, n0 = blockIdx.y * BN;    // m is the FAST grid dim
    A  += (size_t)m0 * lda;
    Bm += (size_t)n0 * ldb;
    f32x4 acc[4][4] = {};
    int lan15 = lane & 15, quad = lane >> 4;
    int sw = lan15 & 7;

    for (int k0 = 0; k0 < Kblk; k0 += 64) {
        stage<BM, NT>(A + k0, lda, lA, wave, lane);
        stage<BN, NT>(Bm + k0, ldb, lB, wave, lane);
        __syncthreads();
        #pragma unroll
        for (int kk = 0; kk < 2; kk++) {
            int kb = kk * 4 + quad;
            int kel = (kb ^ sw) * 8;
            bf16x8 af[4], bfr[4];
            #pragma unroll
            for (int t = 0; t < 4; t++) {
                short8 ra = *(const short8*)(lA + (size_t)(wm * 64 + t * 16 + lan15) * 64 + kel);
                short8 rb = *(const short8*)(lB + (size_t)(wn * 64 + t * 16 + lan15) * 64 + kel);
                af[t]  = __builtin_bit_cast(bf16x8, ra);
                bfr[t] = __builtin_bit_cast(bf16x8, rb);
            }
            #pragma unroll
            for (int mt = 0; mt < 4; mt++)
                #pragma unroll
                for (int nt = 0; nt < 4; nt++)
                    acc[mt][nt] = __builtin_amdgcn_mfma_f32_16x16x32_bf16(af[mt], bfr[nt],
                                                                          acc[mt][nt], 0, 0, 0);
        }
        __syncthreads();
    }

    const int basen[5] = {0, 4, 12, 28, 60};
    unsigned short* H = (unsigned short*)Cout;
    #pragma unroll
    for (int mt = 0; mt < 4; mt++) {
        __syncthreads();
        #pragma unroll
        for (int nt = 0; nt < 4; nt++) {
            int col = n0 + wn * 64 + nt * 16 + lan15;
            int g = col >> 11;
            int ngl = basen[g] + ((col & 2047) >> (9 - g));
            #pragma unroll
            for (int rg = 0; rg < 4; rg++) {
                int grow = m0 + wm * 64 + mt * 16 + quad * 4 + rg;
                float gv = gate[(size_t)grow * NG + ngl];
                lA[wave * 1024 + (quad * 4 + rg) * 64 + nt * 16 + lan15] =
                    f2bf(acc[mt][nt][rg] * gv);
            }
        }
        __syncthreads();
        #pragma unroll
        for (int i = 0; i < 2; i++) {
            int f = i * NT + tid;
            int R = f >> 5;
            int u = f & 31;
            int wv2 = ((R >> 4) << 2) + (u >> 3);
            short8 vread = *(const short8*)(lA + wv2 * 1024 + (R & 15) * 64 + (u & 7) * 8);
            int grow = m0 + (R >> 4) * 64 + mt * 16 + (R & 15);
            *(short8*)(H + (size_t)grow * ldc + n0 + u * 8) = vread;
        }
    }
}

// ---------------- GEMM2: 32x32x16 MFMA, split-K fp32 partial stores ------------
// 16 MFMA per k64 (vs 32 for 16x16x32) at identical LDS traffic — 32x32 sustains
// ~15% higher rate (m119: 2495 vs 2176 TF). C/D: col=lane&31,
// row=(reg&3)+8*(reg>>2)+4*(lane>>5) [m74/m101]; A/B frag k=(lane>>5)*8+j.
__global__ __launch_bounds__(256) void gemm32_nt(const unsigned short* __restrict__ A,
                                                 const unsigned short* __restrict__ Bm,
                                                 int Kblk, int lda, int ldb,
                                                 float* __restrict__ P, int ldc) {
    __shared__ unsigned short lA[128 * 64];
    __shared__ unsigned short lB[128 * 64];
    int tid = threadIdx.x, wave = tid >> 6, lane = tid & 63;
    int wm = wave >> 1, wn = wave & 1;
    int m0 = blockIdx.x * 128, n0 = blockIdx.y * 128;
    A  += (size_t)m0 * lda + (size_t)blockIdx.z * Kblk;
    Bm += (size_t)n0 * ldb + (size_t)blockIdx.z * Kblk;
    f32x16 acc[2][2] = {};
    int lan31 = lane & 31, half = lane >> 5;
    int sw = lan31 & 7;

    for (int k0 = 0; k0 < Kblk; k0 += 64) {
        stage<128, 256>(A + k0, lda, lA, wave, lane);
        stage<128, 256>(Bm + k0, ldb, lB, wave, lane);
        __syncthreads();
        #pragma unroll
        for (int kk = 0; kk < 4; kk++) {
            int kb = kk * 2 + half;             // 16B granule; k = kb*8
            int kel = (kb ^ sw) * 8;
            bf16x8 af[2], bfr[2];
            #pragma unroll
            for (int t = 0; t < 2; t++) {
                short8 ra = *(const short8*)(lA + (size_t)(wm * 64 + t * 32 + lan31) * 64 + kel);
                short8 rb = *(const short8*)(lB + (size_t)(wn * 64 + t * 32 + lan31) * 64 + kel);
                af[t]  = __builtin_bit_cast(bf16x8, ra);
                bfr[t] = __builtin_bit_cast(bf16x8, rb);
            }
            #pragma unroll
            for (int mt = 0; mt < 2; mt++)
                #pragma unroll
                for (int nt = 0; nt < 2; nt++)
                    acc[mt][nt] = __builtin_amdgcn_mfma_f32_32x32x16_bf16(af[mt], bfr[nt],
                                                                          acc[mt][nt], 0, 0, 0);
        }
        __syncthreads();
    }

    P += (size_t)blockIdx.z * gridDim.x * 128 * ldc;
    #pragma unroll
    for (int nt = 0; nt < 2; nt++) {
        int col = n0 + wn * 64 + nt * 32 + lan31;
        #pragma unroll
        for (int mt = 0; mt < 2; mt++) {
            int rbase = m0 + wm * 64 + mt * 32 + 4 * half;
            #pragma unroll
            for (int reg = 0; reg < 16; reg++) {
                int row = rbase + (reg & 3) + 8 * (reg >> 2);
                P[(size_t)row * ldc + col] = acc[mt][nt][reg];
            }
        }
    }
}

// ---------------- split-K reduce + fused final stats (block 0) ----------------

__global__ __launch_bounds__(256) void reduce_k(const float4* __restrict__ P,
                                                float4* __restrict__ out, int quarter,
                                                const float* __restrict__ vslot,
                                                const float* __restrict__ uslot,
                                                const float* __restrict__ gslot,
                                                const float* __restrict__ aslot,
                                                float* __restrict__ o2) {
    int i = blockIdx.x * 256 + threadIdx.x;
    float4 a = P[i], b = P[i + quarter], c = P[i + 2 * quarter], d = P[i + 3 * quarter];
    float4 o;
    o.x = (a.x + b.x) + (c.x + d.x);
    o.y = (a.y + b.y) + (c.y + d.y);
    o.z = (a.z + b.z) + (c.z + d.z);
    o.w = (a.w + b.w) + (c.w + d.w);
    out[i] = o;
    if (blockIdx.x == 0) {
        __shared__ float sh[128];
        const int basen[5] = {0, 4, 12, 28, 60};
        int t = threadIdx.x;
        if (t < 128) {
            float v = 0.f;
            if (t < NG) {
                int g = (t < 4) ? 0 : (t < 12) ? 1 : (t < 28) ? 2 : (t < 60) ? 3 : 4;
                int nloc = t - basen[g];
                int bpseg = 48 >> g;
                float vs = 0.f, us = 0.f;
                int base = g * 192 + nloc * bpseg;
                for (int j = 0; j < bpseg; j++) { vs += vslot[base + j]; us += uslot[base + j]; }
                float gs = 0.f;
                for (int bb = 0; bb < 32; bb++) gs += gslot[bb * NG + t];
                float rr = (float)(512 >> g);
                float mean = gs * (1.0f / BATCH);
                float frob = sqrtf(us * vs) / sqrtf(768.0f * rr);
                v = tanhf(mean) * frob;
            }
            sh[t] = v;
        }
        if (t == 128) {
            float asum = 0.f;
            for (int bb = 0; bb < 32; bb++) asum += aslot[bb];
            o2[1] = asum * (1.0f / BATCH);
        }
        __syncthreads();
        for (int s = 64; s > 0; s >>= 1) {
            if (threadIdx.x < s) sh[threadIdx.x] += sh[threadIdx.x + s];
            __syncthreads();
        }
        if (threadIdx.x == 0) o2[0] = sh[0];
    }
}

// ---------------- launcher ----------------

extern "C" void kernel_launch(void* const* d_in, const int* in_sizes, int n_in,
                              void* d_out, int out_size, void* d_ws, size_t ws_size,
                              hipStream_t stream) {
    const float* x = (const float*)d_in[0];
    Ptr5 vp, up, ep, bp;
    for (int g = 0; g < 5; g++) {
        vp.p[g] = (const float*)d_in[1 + 4 * g];
        up.p[g] = (const float*)d_in[2 + 4 * g];
        ep.p[g] = (const float*)d_in[3 + 4 * g];
        bp.p[g] = (const float*)d_in[4 + 4 * g];
    }
    float* out = (float*)d_out;
    char* ws = (char*)d_ws;
    size_t off = 0;
    unsigned short* xb   = (unsigned short*)(ws + off); off += (size_t)BATCH * DM * 2;
    unsigned short* vb   = (unsigned short*)(ws + off); off += (size_t)LTOT * DM * 2;
    unsigned short* w2t  = (unsigned short*)(ws + off); off += (size_t)LTOT * DM * 2;
    float* gate_ws       = (float*)(ws + off);          off += (size_t)BATCH * NG * 4;
    float* vslot         = (float*)(ws + off);          off += 960 * 4;
    float* uslot         = (float*)(ws + off);          off += 960 * 4;
    float* gslot         = (float*)(ws + off);          off += 32 * NG * 4;
    float* aslot         = (float*)(ws + off);          off += 32 * 4 + 256;
    size_t fixed = off;
    int CB = BATCH;
    while (CB > 128 && fixed + (size_t)CB * LTOT * 2 + 4ull * CB * DM * 4 > ws_size) CB >>= 1;
    unsigned short* Hg  = (unsigned short*)(ws + fixed);
    float* partial      = (float*)(ws + fixed + (size_t)CB * LTOT * 2);

    prep_k<<<dim3(2336), 256, 0, stream>>>(
        x, vp, up, ep, bp, vb, w2t, xb, gate_ws, out,
        vslot, uslot, gslot, aslot);

    int nch = BATCH / CB;
    for (int c = 0; c < nch; c++) {
        // GEMM1: Hg = gate .* (x @ V^T)   (M=CB, N=10240, K=768), m-fast grid
        gemm_nt<128, 256, 512><<<dim3(CB / 128, LTOT / 256, 1), 512, 0, stream>>>(
            xb + (size_t)c * CB * DM, vb, DM, DM, DM,
            (void*)Hg, gate_ws + (size_t)c * CB * NG, LTOT);
        // GEMM2: out = Hg @ W2   (M=CB, N=768, K=10240), split-K=4, 32x32 MFMA
        gemm32_nt<<<dim3(CB / 128, DM / 128, 4), 256, 0, stream>>>(
            Hg, w2t, LTOT / 4, LTOT, LTOT, partial, DM);
        // reduce + fused final stats (block 0)
        reduce_k<<<dim3(CB * 192 / 256), 256, 0, stream>>>(
            (const float4*)partial, (float4*)(out + (size_t)c * CB * DM), CB * DM / 4,
            vslot, uslot, gslot, aslot, out + (size_t)BATCH * DM);
    }
}